// Round 1
// baseline (218.401 us; speedup 1.0000x reference)
//
#include <hip/hip_runtime.h>
#include <cmath>

// Problem constants (from reference)
constexpr int kN    = 3072;
constexpr int kR    = 7;
constexpr int kSPC  = 5;      // SPACE = R - ATTN_R
constexpr int kD    = 64;
constexpr int kWIN  = 128;
constexpr int kTOPK = 16;
constexpr int kE    = kN * 16;       // 49152 edges
constexpr int kRN   = kR * kN;       // 21504 (new_edge_list row width)
constexpr int kRD   = kR * kD;       // 448   (msg2 row width)
constexpr float kEPS = 1e-5f;

__device__ __forceinline__ float wred_max(float v) {
#pragma unroll
  for (int off = 32; off; off >>= 1) v = fmaxf(v, __shfl_xor(v, off));
  return v;
}
__device__ __forceinline__ float wred_sum(float v) {
#pragma unroll
  for (int off = 32; off; off >>= 1) v += __shfl_xor(v, off);
  return v;
}

// ---------------------------------------------------------------------------
// 1) Edge scatter: one wave per edge, lane = feature.
//    r < 5 : msg2[j, (r+2)*64 + d] += w * x[i,d];  NEL[i, (r+2)*N + j] += w
//    r >= 5: msgA[(r-5), j, d]     += w * x[i,d];  NEL[i, (r-5)*N + j] += w
__global__ __launch_bounds__(256) void k_scatter(
    const float* __restrict__ x, const float* __restrict__ ew,
    const int* __restrict__ nin, const int* __restrict__ nout,
    const int* __restrict__ rel,
    float* __restrict__ msg2, float* __restrict__ msgA, float* __restrict__ nel) {
  const int e = blockIdx.x * 4 + (threadIdx.x >> 6);
  const int lane = threadIdx.x & 63;
  const int r = rel[e], i = nin[e], j = nout[e];
  const float w = ew[e];
  const float v = w * x[i * kD + lane];
  if (r < kSPC) {
    atomicAdd(&msg2[(size_t)j * kRD + (r + 2) * kD + lane], v);
    if (lane == 0) atomicAdd(&nel[(size_t)i * kRN + (size_t)(r + 2) * kN + j], w);
  } else {
    const int k = r - kSPC;
    atomicAdd(&msgA[(size_t)(k * kN + j) * kD + lane], v);
    if (lane == 0) atomicAdd(&nel[(size_t)i * kRN + (size_t)k * kN + j], w);
  }
}

// ---------------------------------------------------------------------------
// 2) h1[k,n,e] = msgA[k,n,:]·W_rel_s[5+k,:,e] + x[n,:]·W_self_s[:,e] + b_s[e]
//    (pre-BN). block = 4 rows x 64 cols, grid = (N/4, 2)
__global__ __launch_bounds__(256) void k_h1(
    const float* __restrict__ x, const float* __restrict__ msgA,
    const float* __restrict__ Wrel, const float* __restrict__ Wself,
    const float* __restrict__ bs, float* __restrict__ h1) {
  const int k = blockIdx.y;
  const int e = threadIdx.x & 63;
  const int rl = threadIdx.x >> 6;
  const int n = blockIdx.x * 4 + rl;
  __shared__ float a[4][kD], xx[4][kD];
  a[rl][e] = msgA[(size_t)(k * kN + n) * kD + e];
  xx[rl][e] = x[n * kD + e];
  __syncthreads();
  const float* Wr = Wrel + (size_t)(kSPC + k) * kD * kD;
  float acc = bs[e];
#pragma unroll 8
  for (int d = 0; d < kD; ++d)
    acc += a[rl][d] * Wr[d * kD + e] + xx[rl][d] * Wself[d * kD + e];
  h1[(size_t)(k * kN + n) * kD + e] = acc;
}

// ---------------------------------------------------------------------------
// 3) Column batch-norm stats: one block per column c = mat*64 + e over N rows.
__global__ __launch_bounds__(256) void k_bnstats(
    const float* __restrict__ h, float* __restrict__ mean, float* __restrict__ inv) {
  const int c = blockIdx.x;
  const int mat = c >> 6, e = c & 63;
  const float* p = h + (size_t)mat * kN * kD + e;
  float s = 0.f, s2 = 0.f;
  for (int n = threadIdx.x; n < kN; n += 256) {
    float v = p[(size_t)n * kD];
    s += v; s2 += v * v;
  }
  __shared__ float sh0[256], sh1[256];
  sh0[threadIdx.x] = s; sh1[threadIdx.x] = s2;
  __syncthreads();
  for (int off = 128; off > 0; off >>= 1) {
    if (threadIdx.x < off) { sh0[threadIdx.x] += sh0[threadIdx.x + off]; sh1[threadIdx.x] += sh1[threadIdx.x + off]; }
    __syncthreads();
  }
  if (threadIdx.x == 0) {
    float m = sh0[0] / (float)kN;
    float var = sh1[0] / (float)kN - m * m;
    mean[c] = m;
    inv[c] = rsqrtf(var + kEPS);
  }
}

// ---------------------------------------------------------------------------
// 4) attn_in = relu(BN(h1)); q = attn_in @ Wq[k], kk = attn_in @ Wk[k]
__global__ __launch_bounds__(256) void k_qk(
    const float* __restrict__ h1, const float* __restrict__ mean,
    const float* __restrict__ inv, const float* __restrict__ Wq,
    const float* __restrict__ Wk, float* __restrict__ qb, float* __restrict__ kb) {
  const int k = blockIdx.y;
  const int e = threadIdx.x & 63;
  const int rl = threadIdx.x >> 6;
  const int n = blockIdx.x * 4 + rl;
  __shared__ float a[4][kD];
  float v = h1[(size_t)(k * kN + n) * kD + e];
  v = (v - mean[k * 64 + e]) * inv[k * 64 + e];
  a[rl][e] = v > 0.f ? v : 0.f;
  __syncthreads();
  const float* wq = Wq + (size_t)k * kD * kD;
  const float* wk = Wk + (size_t)k * kD * kD;
  float aq = 0.f, ak = 0.f;
#pragma unroll 8
  for (int d = 0; d < kD; ++d) {
    float av = a[rl][d];
    aq += av * wq[d * kD + e];
    ak += av * wk[d * kD + e];
  }
  qb[(size_t)(k * kN + n) * kD + e] = aq;
  kb[(size_t)(k * kN + n) * kD + e] = ak;
}

// ---------------------------------------------------------------------------
// 5) Attention: one wave per (k, n) row. Windowed scores -> per-head softmax
//    -> head-mean probs -> exact 16th order statistic -> write max(A, p) into
//    NEL output cells, record selected columns, scatter into msg2 attn blocks.
__global__ __launch_bounds__(256) void k_attn(
    const float* __restrict__ qb, const float* __restrict__ kb,
    const float* __restrict__ x, float* __restrict__ nel,
    float* __restrict__ msg2, int* __restrict__ selCols, int* __restrict__ selCnt) {
  const int lane = threadIdx.x & 63;
  const int w = threadIdx.x >> 6;
  const int idx = blockIdx.x * 4 + w;
  const int k = idx / kN;
  const int n = idx - k * kN;
  __shared__ float qs[4][kD];
  __shared__ float sval[4][64];
  __shared__ int scol[4][64];
  qs[w][lane] = qb[(size_t)(k * kN + n) * kD + lane];
  __syncthreads();
  const int lo = n - kWIN < 0 ? 0 : n - kWIN;
  const int hi = n + kWIN > kN - 1 ? kN - 1 : n + kWIN;

  // scores: sc[s][h] = (q[n,h,:]·k[m,h,:]) / sqrt(16) / TEMP = dot * 0.5
  float sc[5][4];
#pragma unroll
  for (int s = 0; s < 5; ++s) {
    const int m = lo + s * 64 + lane;
    if (m <= hi) {
      const float4* krow = reinterpret_cast<const float4*>(kb + (size_t)(k * kN + m) * kD);
#pragma unroll
      for (int h = 0; h < 4; ++h) {
        float acc = 0.f;
#pragma unroll
        for (int g = 0; g < 4; ++g) {
          float4 kv = krow[h * 4 + g];
          const float* qp = &qs[w][h * 16 + g * 4];
          acc += kv.x * qp[0] + kv.y * qp[1] + kv.z * qp[2] + kv.w * qp[3];
        }
        sc[s][h] = acc * 0.5f;
      }
    } else {
#pragma unroll
      for (int h = 0; h < 4; ++h) sc[s][h] = -3.0e38f;
    }
  }

  // per-head windowed softmax, head-mean
  float pm[5] = {0.f, 0.f, 0.f, 0.f, 0.f};
#pragma unroll
  for (int h = 0; h < 4; ++h) {
    float lm = fmaxf(fmaxf(fmaxf(sc[0][h], sc[1][h]), fmaxf(sc[2][h], sc[3][h])), sc[4][h]);
    float mx = wred_max(lm);
    float eh[5], den = 0.f;
#pragma unroll
    for (int s = 0; s < 5; ++s) {
      eh[s] = (sc[s][h] > -1.0e38f) ? expf(sc[s][h] - mx) : 0.f;
      den += eh[s];
    }
    den = wred_sum(den);
    float rdn = 1.f / den;
#pragma unroll
    for (int s = 0; s < 5; ++s) pm[s] += eh[s] * rdn;
  }
#pragma unroll
  for (int s = 0; s < 5; ++s) pm[s] *= 0.25f;

  // exact 16th largest: 16 rounds of remove-one-max (tie-exact)
  float rem[5];
#pragma unroll
  for (int s = 0; s < 5; ++s) {
    const int m = lo + s * 64 + lane;
    rem[s] = (m <= hi) ? pm[s] : -1.f;
  }
  float kth = 0.f;
  for (int t = 0; t < kTOPK; ++t) {
    float lm = fmaxf(fmaxf(fmaxf(rem[0], rem[1]), fmaxf(rem[2], rem[3])), rem[4]);
    float gm = wred_max(lm);
    unsigned long long b = __ballot(lm == gm);
    int src = __ffsll((unsigned long long)b) - 1;
    if (lane == src) {
      if (rem[0] == gm) rem[0] = -2.f;
      else if (rem[1] == gm) rem[1] = -2.f;
      else if (rem[2] == gm) rem[2] = -2.f;
      else if (rem[3] == gm) rem[3] = -2.f;
      else rem[4] = -2.f;
    }
    kth = gm;
  }

  // selection (probs >= kth, tie-inclusive), prefix positions
  bool sel[5];
  int cl = 0;
#pragma unroll
  for (int s = 0; s < 5; ++s) {
    const int m = lo + s * 64 + lane;
    sel[s] = (m <= hi) && (pm[s] >= kth);
    cl += sel[s] ? 1 : 0;
  }
  int v = cl;
#pragma unroll
  for (int off = 1; off < 64; off <<= 1) {
    int t = __shfl_up(v, off);
    if (lane >= off) v += t;
  }
  const int excl = v - cl;
  const int total = __shfl(v, 63);
  const int tot = total < 64 ? total : 64;
  const int rowbase = (k * kN + n) * 64;
  int p = excl;
#pragma unroll
  for (int s = 0; s < 5; ++s) {
    if (sel[s] && p < 64) {
      const int m = lo + s * 64 + lane;
      const size_t cell = (size_t)n * kRN + (size_t)k * kN + m;
      float a = nel[cell];
      float fin = fmaxf(a, pm[s]);   // B = max(A, S) at selected cells
      nel[cell] = fin;
      scol[w][p] = m;
      sval[w][p] = fin;
      selCols[rowbase + p] = m;
      ++p;
    }
  }
  if (lane == 0) selCnt[k * kN + n] = tot;

  // scatter: msg2[m, k*64 + d] += fin * x[n, d]
  const float xv = x[n * kD + lane];
  for (int t = 0; t < tot; ++t) {
    const int m = scol[w][t];
    const float fv = sval[w][t];
    atomicAdd(&msg2[(size_t)m * kRD + k * kD + lane], fv * xv);
  }
}

// ---------------------------------------------------------------------------
// 6) Attention-relation edge fixup: cells NOT selected contribute A (= sum of
//    duplicate edge weights); selected cells were already fully counted.
__global__ __launch_bounds__(256) void k_edgefix(
    const float* __restrict__ x, const float* __restrict__ ew,
    const int* __restrict__ nin, const int* __restrict__ nout,
    const int* __restrict__ rel, const int* __restrict__ selCols,
    const int* __restrict__ selCnt, float* __restrict__ msg2) {
  const int e = blockIdx.x * 4 + (threadIdx.x >> 6);
  const int lane = threadIdx.x & 63;
  const int r = rel[e];
  if (r < kSPC) return;                       // wave-uniform
  const int k = r - kSPC, i = nin[e], j = nout[e];
  int diff = i - j; if (diff < 0) diff = -diff;
  if (diff <= kWIN) {
    const int cnt = selCnt[k * kN + i];
    bool mine = (lane < cnt) && (selCols[(k * kN + i) * 64 + lane] == j);
    if (__ballot(mine)) return;               // cell was selected -> skip
  }
  atomicAdd(&msg2[(size_t)j * kRD + k * kD + lane], ew[e] * x[i * kD + lane]);
}

// ---------------------------------------------------------------------------
// 7) hidden pre-activation: hpre[n,e] = msg2[n,:]·W_msg[:,e] + x[n,:]·Wg[:,e] + bg[e]
__global__ __launch_bounds__(256) void k_hpre(
    const float* __restrict__ msg2, const float* __restrict__ x,
    const float* __restrict__ Wmsg, const float* __restrict__ Wg,
    const float* __restrict__ bg, float* __restrict__ hpre) {
  const int e = threadIdx.x & 63;
  const int rl = threadIdx.x >> 6;
  const int n0 = blockIdx.x * 4;
  __shared__ float ml[4][kRD];
  __shared__ float xl[4][kD];
  for (int idx = threadIdx.x; idx < 4 * kRD; idx += 256) {
    int rr = idx / kRD, c = idx - rr * kRD;
    ml[rr][c] = msg2[(size_t)(n0 + rr) * kRD + c];
  }
  {
    int rr = threadIdx.x >> 6, c = threadIdx.x & 63;
    xl[rr][c] = x[(n0 + rr) * kD + c];
  }
  __syncthreads();
  float acc = bg[e];
#pragma unroll 8
  for (int c = 0; c < kRD; ++c) acc += ml[rl][c] * Wmsg[c * kD + e];
#pragma unroll 8
  for (int d = 0; d < kD; ++d) acc += xl[rl][d] * Wg[d * kD + e];
  hpre[(size_t)(n0 + rl) * kD + e] = acc;
}

// ---------------------------------------------------------------------------
// 8) hidden = relu(BN(hpre)) in place; graph_feature += column sums
__global__ __launch_bounds__(256) void k_hfin(
    float* __restrict__ hid, const float* __restrict__ mean,
    const float* __restrict__ inv, float* __restrict__ gf) {
  const int e = threadIdx.x & 63;
  const int rl = threadIdx.x >> 6;
  const int n = blockIdx.x * 4 + rl;
  float v = hid[(size_t)n * kD + e];
  v = (v - mean[e]) * inv[e];
  v = v > 0.f ? v : 0.f;
  hid[(size_t)n * kD + e] = v;
  __shared__ float sh[4][kD];
  sh[rl][e] = v;
  __syncthreads();
  if (threadIdx.x < 64)
    atomicAdd(&gf[e], sh[0][e] + sh[1][e] + sh[2][e] + sh[3][e]);
}

// ---------------------------------------------------------------------------
extern "C" void kernel_launch(void* const* d_in, const int* in_sizes, int n_in,
                              void* d_out, int out_size, void* d_ws, size_t ws_size,
                              hipStream_t stream) {
  (void)in_sizes; (void)n_in; (void)ws_size;
  const float* x     = (const float*)d_in[0];
  const float* ew    = (const float*)d_in[1];
  const float* Wrel  = (const float*)d_in[2];
  const float* Wself = (const float*)d_in[3];
  const float* bs    = (const float*)d_in[4];
  const float* Wq    = (const float*)d_in[5];
  const float* Wk    = (const float*)d_in[6];
  const float* Wmsg  = (const float*)d_in[7];
  const float* Wg    = (const float*)d_in[8];
  const float* bg    = (const float*)d_in[9];
  const int*   nin   = (const int*)d_in[10];
  const int*   nout  = (const int*)d_in[11];
  const int*   rel   = (const int*)d_in[12];

  float* gf  = (float*)d_out;                    // 64
  float* hid = gf + 64;                          // N*64
  float* nel = hid + (size_t)kN * kD;            // N * R*N

  float* w0    = (float*)d_ws;
  float* msg2  = w0;                             // N*448   (zeroed)
  float* msgA  = msg2 + (size_t)kN * kRD;        // 2*N*64  (zeroed)
  float* h1    = msgA + (size_t)2 * kN * kD;     // 2*N*64
  float* qb    = h1   + (size_t)2 * kN * kD;     // 2*N*64
  float* kb    = qb   + (size_t)2 * kN * kD;     // 2*N*64
  float* mean1 = kb   + (size_t)2 * kN * kD;     // 128
  float* inv1  = mean1 + 128;                    // 128
  float* mean2 = inv1 + 128;                     // 64
  float* inv2  = mean2 + 64;                     // 64
  int* selCols = (int*)(inv2 + 64);              // 2*N*64 ints
  int* selCnt  = selCols + (size_t)2 * kN * 64;  // 2*N ints

  // Full output must be written every call (deterministic; first timed call
  // sees 0xAA poison). memset is the 265 MB floor.
  hipMemsetAsync(d_out, 0, (size_t)out_size * sizeof(float), stream);
  hipMemsetAsync(msg2, 0, (size_t)(kN * kRD + 2 * kN * kD) * sizeof(float), stream);

  k_scatter<<<kE / 4, 256, 0, stream>>>(x, ew, nin, nout, rel, msg2, msgA, nel);
  dim3 g2(kN / 4, 2);
  k_h1<<<g2, 256, 0, stream>>>(x, msgA, Wrel, Wself, bs, h1);
  k_bnstats<<<128, 256, 0, stream>>>(h1, mean1, inv1);
  k_qk<<<g2, 256, 0, stream>>>(h1, mean1, inv1, Wq, Wk, qb, kb);
  k_attn<<<(2 * kN) / 4, 256, 0, stream>>>(qb, kb, x, nel, msg2, selCols, selCnt);
  k_edgefix<<<kE / 4, 256, 0, stream>>>(x, ew, nin, nout, rel, selCols, selCnt, msg2);
  k_hpre<<<kN / 4, 256, 0, stream>>>(msg2, x, Wmsg, Wg, bg, hid);
  k_bnstats<<<64, 256, 0, stream>>>(hid, mean2, inv2);
  k_hfin<<<kN / 4, 256, 0, stream>>>(hid, mean2, inv2, gf);
}